// Round 9
// baseline (1185.675 us; speedup 1.0000x reference)
//
#include <hip/hip_runtime.h>

#define WN 32          // WIDTH
#define HID 8          // WIDTH/4
#define DEPTH 4
#define TS 128         // edges per 16-thread group (edge-balanced gather)

typedef float fvec4 __attribute__((ext_vector_type(4)));

__global__ void zero_kernel(int* __restrict__ cnt, int* __restrict__ cursor,
                            float* __restrict__ agg, int n, int nagg) {
    int i = blockIdx.x * blockDim.x + threadIdx.x;
    if (i < n) { cnt[i] = 0; cursor[i] = 0; }
    if (i < nagg) agg[i] = 0.0f;
}

__global__ void count_kernel(const int* __restrict__ eidx, int* __restrict__ cnt, int e_cnt) {
    int e = blockIdx.x * blockDim.x + threadIdx.x;
    if (e >= e_cnt) return;
    atomicAdd(&cnt[eidx[e_cnt + e]], 1);
}

// --- 3-kernel parallel scan of cnt -> row_ptr (replaces serial single-block scan) ---
__global__ void scan1_kernel(const int* __restrict__ cnt, int* __restrict__ blk_sum, int n) {
    __shared__ int s_wave[4];
    int t = threadIdx.x;
    int lane = t & 63, wv = t >> 6;
    int i = blockIdx.x * 256 + t;
    int v = (i < n) ? cnt[i] : 0;
#pragma unroll
    for (int d = 1; d < 64; d <<= 1) v += __shfl_xor(v, d, 64);
    if (lane == 0) s_wave[wv] = v;
    __syncthreads();
    if (t == 0) blk_sum[blockIdx.x] = s_wave[0] + s_wave[1] + s_wave[2] + s_wave[3];
}

__global__ void scan2_kernel(const int* __restrict__ blk_sum, int* __restrict__ blk_base, int nblk) {
    __shared__ int s_wave[4];
    int t = threadIdx.x;
    int lane = t & 63, wv = t >> 6;
    int offset = 0;
    for (int base = 0; base < nblk; base += 256) {
        int i = base + t;
        int v = (i < nblk) ? blk_sum[i] : 0;
        int x = v;
#pragma unroll
        for (int d = 1; d < 64; d <<= 1) {
            int y = __shfl_up(x, d, 64);
            if (lane >= d) x += y;
        }
        if (lane == 63) s_wave[wv] = x;
        __syncthreads();
        if (wv == 0 && lane < 4) {
            int y = s_wave[lane];
#pragma unroll
            for (int d = 1; d < 4; d <<= 1) {
                int z = __shfl_up(y, d, 64);
                if (lane >= d) y += z;
            }
            s_wave[lane] = y;
        }
        __syncthreads();
        int waveoff = (wv > 0) ? s_wave[wv - 1] : 0;
        int total = s_wave[3];
        if (i < nblk) blk_base[i] = x + waveoff + offset - v;   // exclusive
        offset += total;
        __syncthreads();
    }
}

__global__ void scan3_kernel(const int* __restrict__ cnt, const int* __restrict__ blk_base,
                             int* __restrict__ row_ptr, float* __restrict__ inv, int n) {
    __shared__ int s_wave[4];
    int t = threadIdx.x;
    int lane = t & 63, wv = t >> 6;
    int i = blockIdx.x * 256 + t;
    int v = (i < n) ? cnt[i] : 0;
    int x = v;
#pragma unroll
    for (int d = 1; d < 64; d <<= 1) {
        int y = __shfl_up(x, d, 64);
        if (lane >= d) x += y;
    }
    if (lane == 63) s_wave[wv] = x;
    __syncthreads();
    if (wv == 0 && lane < 4) {
        int y = s_wave[lane];
#pragma unroll
        for (int d = 1; d < 4; d <<= 1) {
            int z = __shfl_up(y, d, 64);
            if (lane >= d) y += z;
        }
        s_wave[lane] = y;
    }
    __syncthreads();
    int waveoff = (wv > 0) ? s_wave[wv - 1] : 0;
    if (i < n) {
        row_ptr[i + 1] = blk_base[blockIdx.x] + waveoff + x;   // inclusive + block base
        inv[i] = 1.0f / (float)(v > 1 ? v : 1);
    }
    if (i == 0) row_ptr[0] = 0;
}

// Permute edges into dst-CSR order as ONE packed 16B record per edge.
__global__ void scatter_kernel(const int* __restrict__ eidx, const float* __restrict__ ea,
                               const int* __restrict__ row_ptr, int* __restrict__ cursor,
                               fvec4* __restrict__ rec, int e_cnt) {
    int e = blockIdx.x * blockDim.x + threadIdx.x;
    if (e >= e_cnt) return;
    int src = eidx[e];
    int dst = eidx[e_cnt + e];
    int pos = row_ptr[dst] + atomicAdd(&cursor[dst], 1);
    fvec4 r;
    r.x = __int_as_float(src);
    r.y = ea[3 * e];
    r.z = ea[3 * e + 1];
    r.w = ea[3 * e + 2];
    rec[pos] = r;
}

__global__ void h0_kernel(const float* __restrict__ x, const float* __restrict__ fc1_w,
                          const float* __restrict__ fc1_b, float* __restrict__ h, int n) {
    __shared__ float s_w[WN * 3];
    __shared__ float s_b[WN];
    int t = threadIdx.x;
    if (t < WN * 3) s_w[t] = fc1_w[t];
    if (t < WN) s_b[t] = fc1_b[t];
    __syncthreads();
    int i = blockIdx.x * blockDim.x + t;
    if (i >= n) return;
    float x0 = x[3 * i], x1 = x[3 * i + 1], x2 = x[3 * i + 2];
#pragma unroll
    for (int j = 0; j < WN; j++) {
        h[(size_t)i * WN + j] = s_b[j] + s_w[j * 3] * x0 + s_w[j * 3 + 1] * x1 + s_w[j * 3 + 2] * x2;
    }
}

// Edge-balanced, barrier-free gather. Block = 16 groups x 16 ch-threads
// (2 channels each). Each group owns a fixed TS-edge CSR range: perfect
// balance, no __syncthreads (group is a quarter-wave -> lockstep, in-order
// DS pipe; wave_barrier only pins compiler ordering). Stage 16 recs
// (coalesced, hid recomputed in-register), serial inner loop over LDS.
// Segment ends from row_ptr: interior nodes plain-store their full sum,
// boundary nodes (<=2/tile) atomicAdd partial sums into agg.
__global__ void gather_edge_kernel(const int* __restrict__ row_ptr, const fvec4* __restrict__ rec,
                                   const float* __restrict__ h_in, float* __restrict__ agg,
                                   const float* __restrict__ kw1, const float* __restrict__ kb1,
                                   const float* __restrict__ kw2, const float* __restrict__ kb2,
                                   int n, int e_cnt) {
    __shared__ int   s_src[16][17];
    __shared__ fvec4 s_u[16][17];
    __shared__ fvec4 s_v[16][17];
    int t = threadIdx.x;
    int g = t >> 4, tc = t & 15;
    long gid = (long)blockIdx.x * 16 + g;
    int a = (int)(gid * TS);
    if (a >= e_cnt) return;
    int b = a + TS;
    if (b > e_cnt) b = e_cnt;

    const fvec4* kwp = (const fvec4*)(kw2 + tc * 16);
    fvec4 wa0 = kwp[0], wa1 = kwp[1];        // channel 2tc
    fvec4 wb0 = kwp[2], wb1 = kwp[3];        // channel 2tc+1
    float2 b2 = *(const float2*)(kb2 + 2 * tc);

    // binary search: dst with row_ptr[dst] <= a < row_ptr[dst+1]
    int lo = 0, hi = n - 1;
    while (lo < hi) {
        int mid = (lo + hi + 1) >> 1;
        if (row_ptr[mid] <= a) lo = mid; else hi = mid - 1;
    }
    int dst = lo;
    int next_end = row_ptr[dst + 1];
    bool seg_plain = (row_ptr[dst] == a);    // segment fully starts in this tile

    float acc0 = 0.0f, acc1 = 0.0f;
    for (int sb = a; sb < b; sb += 16) {
        int e = sb + tc;
        if (e < b) {
            fvec4 r = rec[e];
            s_src[g][tc] = __float_as_int(r.x);
            float hv[HID];
#pragma unroll
            for (int j = 0; j < HID; j++) {
                float u = kb1[j] + kw1[3 * j] * r.y + kw1[3 * j + 1] * r.z + kw1[3 * j + 2] * r.w;
                hv[j] = u > 0.0f ? u : 0.0f;
            }
            fvec4 lo4, hi4;
            lo4.x = hv[0]; lo4.y = hv[1]; lo4.z = hv[2]; lo4.w = hv[3];
            hi4.x = hv[4]; hi4.y = hv[5]; hi4.z = hv[6]; hi4.w = hv[7];
            s_u[g][tc] = lo4;
            s_v[g][tc] = hi4;
        }
        __builtin_amdgcn_wave_barrier();     // pin LDS write->read order (HW is in-order per wave)
        int cnt = b - sb;
        if (cnt > 16) cnt = 16;
        for (int j = 0; j < cnt; j++) {
            int src = s_src[g][j];
            fvec4 u = s_u[g][j];
            fvec4 v = s_v[g][j];
            float w0 = b2.x + wa0.x * u.x + wa0.y * u.y + wa0.z * u.z + wa0.w * u.w
                            + wa1.x * v.x + wa1.y * v.y + wa1.z * v.z + wa1.w * v.w;
            float w1 = b2.y + wb0.x * u.x + wb0.y * u.y + wb0.z * u.z + wb0.w * u.w
                            + wb1.x * v.x + wb1.y * v.y + wb1.z * v.z + wb1.w * v.w;
            float2 hh = *(const float2*)(h_in + (size_t)src * WN + 2 * tc);
            acc0 += hh.x * w0;
            acc1 += hh.y * w1;
            int enext = sb + j + 1;
            if (enext == next_end) {
                float* ap = agg + (size_t)dst * WN + 2 * tc;
                if (seg_plain) { ap[0] = acc0; ap[1] = acc1; }
                else { atomicAdd(ap, acc0); atomicAdd(ap + 1, acc1); }
                acc0 = 0.0f; acc1 = 0.0f;
                seg_plain = true;
                dst++;
                while (dst < n && row_ptr[dst + 1] == enext) dst++;   // skip deg-0 nodes
                next_end = (dst < n) ? row_ptr[dst + 1] : 0x7FFFFFFF;
            }
        }
        __builtin_amdgcn_wave_barrier();
    }
    if (b < next_end) {                      // partial tail segment -> atomic
        float* ap = agg + (size_t)dst * WN + 2 * tc;
        atomicAdd(ap, acc0);
        atomicAdd(ap + 1, acc1);
    }
}

// Node-parallel epilogue: h_out = relu(agg*inv + h_in@root + cbias);
// re-zeroes agg for the next layer.
__global__ void update_kernel(const float* __restrict__ h_in, float* __restrict__ h_out,
                              float* __restrict__ agg, const float* __restrict__ inv,
                              const float* __restrict__ root, const float* __restrict__ cbias,
                              int n) {
    __shared__ float s_root[WN * WN];
    __shared__ float s_h[8][WN];
    int t = threadIdx.x;
    for (int i = t; i < WN * WN; i += 256) s_root[i] = root[i];
    int grp = t >> 5, ch = t & 31;
    int node = blockIdx.x * 8 + grp;
    float hval = (node < n) ? h_in[(size_t)node * WN + ch] : 0.0f;
    s_h[grp][ch] = hval;
    __syncthreads();
    if (node >= n) return;
    size_t idx = (size_t)node * WN + ch;
    float acc = agg[idx] * inv[node] + cbias[ch];
    agg[idx] = 0.0f;
    const float* srow = s_h[grp];
#pragma unroll
    for (int k = 0; k < WN; k++) acc += srow[k] * s_root[k * WN + ch];
    h_out[idx] = acc > 0.0f ? acc : 0.0f;
}

__global__ void out_kernel(const float* __restrict__ h, const float* __restrict__ fc2_w,
                           const float* __restrict__ fc2_b, float* __restrict__ out, int n) {
    __shared__ float s_w[WN];
    __shared__ float s_b;
    int t = threadIdx.x;
    if (t < WN) s_w[t] = fc2_w[t];
    if (t == 0) s_b = fc2_b[0];
    __syncthreads();
    int i = blockIdx.x * blockDim.x + t;
    if (i >= n) return;
    float acc = s_b;
#pragma unroll
    for (int k = 0; k < WN; k++) acc += h[(size_t)i * WN + k] * s_w[k];
    out[i] = acc;
}

extern "C" void kernel_launch(void* const* d_in, const int* in_sizes, int n_in,
                              void* d_out, int out_size, void* d_ws, size_t ws_size,
                              hipStream_t stream) {
    const float* x      = (const float*)d_in[0];
    const int*   eidx   = (const int*)d_in[1];
    const float* ea     = (const float*)d_in[2];
    const float* fc1_w  = (const float*)d_in[3];
    const float* fc1_b  = (const float*)d_in[4];
    const float* fc2_w  = (const float*)d_in[5];
    const float* fc2_b  = (const float*)d_in[6];
    const float* kw1    = (const float*)d_in[7];
    const float* kb1    = (const float*)d_in[8];
    const float* kw2    = (const float*)d_in[9];
    const float* kb2    = (const float*)d_in[10];
    const float* root   = (const float*)d_in[11];
    const float* cbias  = (const float*)d_in[12];
    float* out = (float*)d_out;

    const int n = in_sizes[0] / 3;       // 50000
    const int e_cnt = in_sizes[2] / 3;   // 1600000

    // workspace layout (floats, 16B-aligned sections)
    auto pad4 = [](size_t v) { return (v + 3) & ~(size_t)3; };
    float* ws = (float*)d_ws;
    size_t off = 0;
    float* hA       = ws + off; off += pad4((size_t)n * WN);
    float* hB       = ws + off; off += pad4((size_t)n * WN);
    float* agg      = ws + off; off += pad4((size_t)n * WN);
    float* inv      = ws + off; off += pad4(n);
    int*   cnt      = (int*)(ws + off); off += pad4(n);
    int*   cursor   = (int*)(ws + off); off += pad4(n);
    int*   row_ptr  = (int*)(ws + off); off += pad4(n + 1);
    int*   blk_sum  = (int*)(ws + off); off += pad4((n + 255) / 256);
    int*   blk_base = (int*)(ws + off); off += pad4((n + 255) / 256);
    fvec4* rec      = (fvec4*)(ws + off); off += (size_t)4 * e_cnt;

    const int B = 256;
    int nagg    = n * WN;
    int grid_nw = (nagg + B - 1) / B;
    int grid_n  = (n + B - 1) / B;
    int grid_e  = (e_cnt + B - 1) / B;
    int nblk    = (n + 255) / 256;
    int ngroups = (e_cnt + TS - 1) / TS;
    int grid_ge = (ngroups + 15) / 16;
    int grid_u  = (n + 7) / 8;

    zero_kernel<<<grid_nw, B, 0, stream>>>(cnt, cursor, agg, n, nagg);
    count_kernel<<<grid_e, B, 0, stream>>>(eidx, cnt, e_cnt);
    scan1_kernel<<<nblk, B, 0, stream>>>(cnt, blk_sum, n);
    scan2_kernel<<<1, B, 0, stream>>>(blk_sum, blk_base, nblk);
    scan3_kernel<<<nblk, B, 0, stream>>>(cnt, blk_base, row_ptr, inv, n);
    scatter_kernel<<<grid_e, B, 0, stream>>>(eidx, ea, row_ptr, cursor, rec, e_cnt);
    h0_kernel<<<grid_n, B, 0, stream>>>(x, fc1_w, fc1_b, hA, n);

    float* hin = hA;
    float* hout = hB;
    for (int d = 0; d < DEPTH; d++) {
        for (int c = 0; c < 3; c++) {
            gather_edge_kernel<<<grid_ge, B, 0, stream>>>(
                row_ptr, rec, hin, agg,
                kw1 + (size_t)c * HID * 3, kb1 + (size_t)c * HID,
                kw2 + (size_t)c * WN * HID, kb2 + (size_t)c * WN, n, e_cnt);
            update_kernel<<<grid_u, B, 0, stream>>>(
                hin, hout, agg, inv,
                root + (size_t)c * WN * WN, cbias + (size_t)c * WN, n);
            float* tmp = hin; hin = hout; hout = tmp;
        }
    }
    // 12 swaps -> final h is in hin
    out_kernel<<<grid_n, B, 0, stream>>>(hin, fc2_w, fc2_b, out, n);
}

// Round 10
// 822.853 us; speedup vs baseline: 1.4409x; 1.4409x over previous
//
#include <hip/hip_runtime.h>

#define WN 32          // WIDTH
#define HID 8          // WIDTH/4
#define DEPTH 4
#define GPB 32         // node-groups per block (32 groups x 8 threads x 4 channels)

typedef float fvec4 __attribute__((ext_vector_type(4)));

__global__ void zero_kernel(int* __restrict__ cnt, int* __restrict__ cursor, int n) {
    int i = blockIdx.x * blockDim.x + threadIdx.x;
    if (i < n) { cnt[i] = 0; cursor[i] = 0; }
}

__global__ void count_kernel(const int* __restrict__ eidx, int* __restrict__ cnt, int e_cnt) {
    int e = blockIdx.x * blockDim.x + threadIdx.x;
    if (e >= e_cnt) return;
    atomicAdd(&cnt[eidx[e_cnt + e]], 1);
}

// --- 3-kernel parallel scan of cnt -> row_ptr (R8-proven) ---
__global__ void scan1_kernel(const int* __restrict__ cnt, int* __restrict__ blk_sum, int n) {
    __shared__ int s_wave[4];
    int t = threadIdx.x;
    int lane = t & 63, wv = t >> 6;
    int i = blockIdx.x * 256 + t;
    int v = (i < n) ? cnt[i] : 0;
#pragma unroll
    for (int d = 1; d < 64; d <<= 1) v += __shfl_xor(v, d, 64);
    if (lane == 0) s_wave[wv] = v;
    __syncthreads();
    if (t == 0) blk_sum[blockIdx.x] = s_wave[0] + s_wave[1] + s_wave[2] + s_wave[3];
}

__global__ void scan2_kernel(const int* __restrict__ blk_sum, int* __restrict__ blk_base, int nblk) {
    __shared__ int s_wave[4];
    int t = threadIdx.x;
    int lane = t & 63, wv = t >> 6;
    int offset = 0;
    for (int base = 0; base < nblk; base += 256) {
        int i = base + t;
        int v = (i < nblk) ? blk_sum[i] : 0;
        int x = v;
#pragma unroll
        for (int d = 1; d < 64; d <<= 1) {
            int y = __shfl_up(x, d, 64);
            if (lane >= d) x += y;
        }
        if (lane == 63) s_wave[wv] = x;
        __syncthreads();
        if (wv == 0 && lane < 4) {
            int y = s_wave[lane];
#pragma unroll
            for (int d = 1; d < 4; d <<= 1) {
                int z = __shfl_up(y, d, 64);
                if (lane >= d) y += z;
            }
            s_wave[lane] = y;
        }
        __syncthreads();
        int waveoff = (wv > 0) ? s_wave[wv - 1] : 0;
        int total = s_wave[3];
        if (i < nblk) blk_base[i] = x + waveoff + offset - v;   // exclusive
        offset += total;
        __syncthreads();
    }
}

__global__ void scan3_kernel(const int* __restrict__ cnt, const int* __restrict__ blk_base,
                             int* __restrict__ row_ptr, float* __restrict__ inv, int n) {
    __shared__ int s_wave[4];
    int t = threadIdx.x;
    int lane = t & 63, wv = t >> 6;
    int i = blockIdx.x * 256 + t;
    int v = (i < n) ? cnt[i] : 0;
    int x = v;
#pragma unroll
    for (int d = 1; d < 64; d <<= 1) {
        int y = __shfl_up(x, d, 64);
        if (lane >= d) x += y;
    }
    if (lane == 63) s_wave[wv] = x;
    __syncthreads();
    if (wv == 0 && lane < 4) {
        int y = s_wave[lane];
#pragma unroll
        for (int d = 1; d < 4; d <<= 1) {
            int z = __shfl_up(y, d, 64);
            if (lane >= d) y += z;
        }
        s_wave[lane] = y;
    }
    __syncthreads();
    int waveoff = (wv > 0) ? s_wave[wv - 1] : 0;
    if (i < n) {
        row_ptr[i + 1] = blk_base[blockIdx.x] + waveoff + x;
        inv[i] = 1.0f / (float)(v > 1 ? v : 1);
    }
    if (i == 0) row_ptr[0] = 0;
}

// Permute edges into dst-CSR order as ONE packed 16B record per edge.
__global__ void scatter_kernel(const int* __restrict__ eidx, const float* __restrict__ ea,
                               const int* __restrict__ row_ptr, int* __restrict__ cursor,
                               fvec4* __restrict__ rec, int e_cnt) {
    int e = blockIdx.x * blockDim.x + threadIdx.x;
    if (e >= e_cnt) return;
    int src = eidx[e];
    int dst = eidx[e_cnt + e];
    int pos = row_ptr[dst] + atomicAdd(&cursor[dst], 1);
    fvec4 r;
    r.x = __int_as_float(src);
    r.y = ea[3 * e];
    r.z = ea[3 * e + 1];
    r.w = ea[3 * e + 2];
    rec[pos] = r;
}

__global__ void h0_kernel(const float* __restrict__ x, const float* __restrict__ fc1_w,
                          const float* __restrict__ fc1_b, float* __restrict__ h, int n) {
    __shared__ float s_w[WN * 3];
    __shared__ float s_b[WN];
    int t = threadIdx.x;
    if (t < WN * 3) s_w[t] = fc1_w[t];
    if (t < WN) s_b[t] = fc1_b[t];
    __syncthreads();
    int i = blockIdx.x * blockDim.x + t;
    if (i >= n) return;
    float x0 = x[3 * i], x1 = x[3 * i + 1], x2 = x[3 * i + 2];
#pragma unroll
    for (int j = 0; j < WN; j++) {
        h[(size_t)i * WN + j] = s_b[j] + s_w[j * 3] * x0 + s_w[j * 3 + 1] * x1 + s_w[j * 3 + 2] * x2;
    }
}

// Cooperative gather, 4-channel register blocking (R6 structure, halved DS
// traffic). 32 node-groups x 8 threads; thread owns channels 4tc..4tc+3.
// Per 16-edge chunk: stage recs (hid recomputed in-register), inner loop
// reads LDS broadcasts + independent coalesced fvec4 h-gather (group of 8
// threads covers the full 128B h-row). Fused epilogue.
__global__ void gather4_kernel(const int* __restrict__ row_ptr, const fvec4* __restrict__ rec,
                               const float* __restrict__ h_in, float* __restrict__ h_out,
                               const float* __restrict__ inv,
                               const float* __restrict__ kw1, const float* __restrict__ kb1,
                               const float* __restrict__ kw2, const float* __restrict__ kb2,
                               const float* __restrict__ root, const float* __restrict__ cbias,
                               int n) {
    __shared__ float s_root[WN * 36];        // stride 36: 16B-aligned fvec4 rows, bank-spread
    __shared__ float s_h[GPB * 36];
    __shared__ int   s_src[GPB][17];
    __shared__ fvec4 s_u[GPB][17];
    __shared__ fvec4 s_v[GPB][17];
    __shared__ int   s_maxdeg;

    int t = threadIdx.x;
    if (t == 0) s_maxdeg = 0;
    for (int i = t; i < WN * WN; i += 256) s_root[(i >> 5) * 36 + (i & 31)] = root[i];

    int grp = t >> 3;          // 0..31
    int tc  = t & 7;           // channels 4tc..4tc+3
    int node = blockIdx.x * GPB + grp;
    bool valid = node < n;

    // per-thread weight columns for 4 output channels (32 floats, coalesced)
    const fvec4* kwp = (const fvec4*)(kw2 + tc * 32);
    fvec4 w0a = kwp[0], w0b = kwp[1];        // ch 4tc
    fvec4 w1a = kwp[2], w1b = kwp[3];        // ch 4tc+1
    fvec4 w2a = kwp[4], w2b = kwp[5];        // ch 4tc+2
    fvec4 w3a = kwp[6], w3b = kwp[7];        // ch 4tc+3
    fvec4 b2 = *(const fvec4*)(kb2 + 4 * tc);
    fvec4 cb = *(const fvec4*)(cbias + 4 * tc);

    int e0 = 0, e1 = 0;
    fvec4 hself = {0.0f, 0.0f, 0.0f, 0.0f};
    if (valid) {
        e0 = row_ptr[node];
        e1 = row_ptr[node + 1];
        hself = *(const fvec4*)(h_in + (size_t)node * WN + 4 * tc);
    }
    *(fvec4*)&s_h[grp * 36 + 4 * tc] = hself;
    int deg = e1 - e0;
    __syncthreads();                         // s_maxdeg init + s_root/s_h visible
    if (valid && tc == 0 && deg > 0) atomicMax(&s_maxdeg, deg);
    __syncthreads();
    int nchunk = (s_maxdeg + 15) >> 4;       // block-uniform

    fvec4 acc = {0.0f, 0.0f, 0.0f, 0.0f};
    for (int cs = 0; cs < nchunk; cs++) {
        int ebase = e0 + (cs << 4);
#pragma unroll
        for (int s = 0; s < 2; s++) {
            int li = tc + (s << 3);
            int e = ebase + li;
            if (e < e1) {
                fvec4 r = rec[e];
                s_src[grp][li] = __float_as_int(r.x);
                float hv[HID];
#pragma unroll
                for (int j = 0; j < HID; j++) {
                    float u = kb1[j] + kw1[3 * j] * r.y + kw1[3 * j + 1] * r.z + kw1[3 * j + 2] * r.w;
                    hv[j] = u > 0.0f ? u : 0.0f;
                }
                fvec4 lo4, hi4;
                lo4.x = hv[0]; lo4.y = hv[1]; lo4.z = hv[2]; lo4.w = hv[3];
                hi4.x = hv[4]; hi4.y = hv[5]; hi4.z = hv[6]; hi4.w = hv[7];
                s_u[grp][li] = lo4;
                s_v[grp][li] = hi4;
            }
        }
        __syncthreads();
        int rem = e1 - ebase;
        int cnt = rem < 16 ? rem : 16;       // <=0 for finished/invalid groups
#pragma unroll 4
        for (int i = 0; i < cnt; i++) {
            int src = s_src[grp][i];
            fvec4 u = s_u[grp][i];
            fvec4 v = s_v[grp][i];
            float w0 = b2.x + w0a.x * u.x + w0a.y * u.y + w0a.z * u.z + w0a.w * u.w
                            + w0b.x * v.x + w0b.y * v.y + w0b.z * v.z + w0b.w * v.w;
            float w1 = b2.y + w1a.x * u.x + w1a.y * u.y + w1a.z * u.z + w1a.w * u.w
                            + w1b.x * v.x + w1b.y * v.y + w1b.z * v.z + w1b.w * v.w;
            float w2 = b2.z + w2a.x * u.x + w2a.y * u.y + w2a.z * u.z + w2a.w * u.w
                            + w2b.x * v.x + w2b.y * v.y + w2b.z * v.z + w2b.w * v.w;
            float w3 = b2.w + w3a.x * u.x + w3a.y * u.y + w3a.z * u.z + w3a.w * u.w
                            + w3b.x * v.x + w3b.y * v.y + w3b.z * v.z + w3b.w * v.w;
            fvec4 hh = *(const fvec4*)(h_in + (size_t)src * WN + 4 * tc);
            acc.x += hh.x * w0;
            acc.y += hh.y * w1;
            acc.z += hh.z * w2;
            acc.w += hh.w * w3;
        }
        __syncthreads();
    }
    if (!valid) return;

    float invn = inv[node];
    fvec4 r;
    r.x = acc.x * invn + cb.x;
    r.y = acc.y * invn + cb.y;
    r.z = acc.z * invn + cb.z;
    r.w = acc.w * invn + cb.w;
#pragma unroll
    for (int k = 0; k < WN; k++) {
        float hk = s_h[grp * 36 + k];
        fvec4 rt = *(const fvec4*)&s_root[k * 36 + 4 * tc];
        r.x += hk * rt.x;
        r.y += hk * rt.y;
        r.z += hk * rt.z;
        r.w += hk * rt.w;
    }
    fvec4 o;
    o.x = r.x > 0.0f ? r.x : 0.0f;
    o.y = r.y > 0.0f ? r.y : 0.0f;
    o.z = r.z > 0.0f ? r.z : 0.0f;
    o.w = r.w > 0.0f ? r.w : 0.0f;
    *(fvec4*)(h_out + (size_t)node * WN + 4 * tc) = o;
}

__global__ void out_kernel(const float* __restrict__ h, const float* __restrict__ fc2_w,
                           const float* __restrict__ fc2_b, float* __restrict__ out, int n) {
    __shared__ float s_w[WN];
    __shared__ float s_b;
    int t = threadIdx.x;
    if (t < WN) s_w[t] = fc2_w[t];
    if (t == 0) s_b = fc2_b[0];
    __syncthreads();
    int i = blockIdx.x * blockDim.x + t;
    if (i >= n) return;
    float acc = s_b;
#pragma unroll
    for (int k = 0; k < WN; k++) acc += h[(size_t)i * WN + k] * s_w[k];
    out[i] = acc;
}

extern "C" void kernel_launch(void* const* d_in, const int* in_sizes, int n_in,
                              void* d_out, int out_size, void* d_ws, size_t ws_size,
                              hipStream_t stream) {
    const float* x      = (const float*)d_in[0];
    const int*   eidx   = (const int*)d_in[1];
    const float* ea     = (const float*)d_in[2];
    const float* fc1_w  = (const float*)d_in[3];
    const float* fc1_b  = (const float*)d_in[4];
    const float* fc2_w  = (const float*)d_in[5];
    const float* fc2_b  = (const float*)d_in[6];
    const float* kw1    = (const float*)d_in[7];
    const float* kb1    = (const float*)d_in[8];
    const float* kw2    = (const float*)d_in[9];
    const float* kb2    = (const float*)d_in[10];
    const float* root   = (const float*)d_in[11];
    const float* cbias  = (const float*)d_in[12];
    float* out = (float*)d_out;

    const int n = in_sizes[0] / 3;       // 50000
    const int e_cnt = in_sizes[2] / 3;   // 1600000

    // workspace layout (floats, 16B-aligned sections)
    auto pad4 = [](size_t v) { return (v + 3) & ~(size_t)3; };
    float* ws = (float*)d_ws;
    size_t off = 0;
    float* hA       = ws + off; off += pad4((size_t)n * WN);
    float* hB       = ws + off; off += pad4((size_t)n * WN);
    float* inv      = ws + off; off += pad4(n);
    int*   cnt      = (int*)(ws + off); off += pad4(n);
    int*   cursor   = (int*)(ws + off); off += pad4(n);
    int*   row_ptr  = (int*)(ws + off); off += pad4(n + 1);
    int*   blk_sum  = (int*)(ws + off); off += pad4((n + 255) / 256);
    int*   blk_base = (int*)(ws + off); off += pad4((n + 255) / 256);
    fvec4* rec      = (fvec4*)(ws + off); off += (size_t)4 * e_cnt;

    const int B = 256;
    int grid_n  = (n + B - 1) / B;
    int grid_e  = (e_cnt + B - 1) / B;
    int nblk    = (n + 255) / 256;
    int grid_g  = (n + GPB - 1) / GPB;

    zero_kernel<<<grid_n, B, 0, stream>>>(cnt, cursor, n);
    count_kernel<<<grid_e, B, 0, stream>>>(eidx, cnt, e_cnt);
    scan1_kernel<<<nblk, B, 0, stream>>>(cnt, blk_sum, n);
    scan2_kernel<<<1, B, 0, stream>>>(blk_sum, blk_base, nblk);
    scan3_kernel<<<nblk, B, 0, stream>>>(cnt, blk_base, row_ptr, inv, n);
    scatter_kernel<<<grid_e, B, 0, stream>>>(eidx, ea, row_ptr, cursor, rec, e_cnt);
    h0_kernel<<<grid_n, B, 0, stream>>>(x, fc1_w, fc1_b, hA, n);

    float* hin = hA;
    float* hout = hB;
    for (int d = 0; d < DEPTH; d++) {
        for (int c = 0; c < 3; c++) {
            gather4_kernel<<<grid_g, B, 0, stream>>>(
                row_ptr, rec, hin, hout, inv,
                kw1 + (size_t)c * HID * 3, kb1 + (size_t)c * HID,
                kw2 + (size_t)c * WN * HID, kb2 + (size_t)c * WN,
                root + (size_t)c * WN * WN, cbias + (size_t)c * WN, n);
            float* tmp = hin; hin = hout; hout = tmp;
        }
    }
    // 12 swaps -> final h is in hin
    out_kernel<<<grid_n, B, 0, stream>>>(hin, fc2_w, fc2_b, out, n);
}

// Round 11
// 670.364 us; speedup vs baseline: 1.7687x; 1.2275x over previous
//
#include <hip/hip_runtime.h>

#define WN 32          // WIDTH
#define HID 8          // WIDTH/4
#define DEPTH 4
#define GPB 16         // node-groups per block (16 threads x 2 channels each) — R6-proven

typedef float fvec4 __attribute__((ext_vector_type(4)));

__global__ void zero_kernel(int* __restrict__ cnt, int n) {
    int i = blockIdx.x * blockDim.x + threadIdx.x;
    if (i < n) cnt[i] = 0;
}

// One atomic pass: produces per-node degree (cnt) AND each edge's rank
// within its destination segment. Replaces separate count + cursor atomics.
__global__ void rank_kernel(const int* __restrict__ eidx, int* __restrict__ cnt,
                            int* __restrict__ rank, int e_cnt) {
    int e = blockIdx.x * blockDim.x + threadIdx.x;
    if (e >= e_cnt) return;
    rank[e] = atomicAdd(&cnt[eidx[e_cnt + e]], 1);
}

// --- 3-kernel parallel scan of cnt -> row_ptr (R8-proven) ---
__global__ void scan1_kernel(const int* __restrict__ cnt, int* __restrict__ blk_sum, int n) {
    __shared__ int s_wave[4];
    int t = threadIdx.x;
    int lane = t & 63, wv = t >> 6;
    int i = blockIdx.x * 256 + t;
    int v = (i < n) ? cnt[i] : 0;
#pragma unroll
    for (int d = 1; d < 64; d <<= 1) v += __shfl_xor(v, d, 64);
    if (lane == 0) s_wave[wv] = v;
    __syncthreads();
    if (t == 0) blk_sum[blockIdx.x] = s_wave[0] + s_wave[1] + s_wave[2] + s_wave[3];
}

__global__ void scan2_kernel(const int* __restrict__ blk_sum, int* __restrict__ blk_base, int nblk) {
    __shared__ int s_wave[4];
    int t = threadIdx.x;
    int lane = t & 63, wv = t >> 6;
    int offset = 0;
    for (int base = 0; base < nblk; base += 256) {
        int i = base + t;
        int v = (i < nblk) ? blk_sum[i] : 0;
        int x = v;
#pragma unroll
        for (int d = 1; d < 64; d <<= 1) {
            int y = __shfl_up(x, d, 64);
            if (lane >= d) x += y;
        }
        if (lane == 63) s_wave[wv] = x;
        __syncthreads();
        if (wv == 0 && lane < 4) {
            int y = s_wave[lane];
#pragma unroll
            for (int d = 1; d < 4; d <<= 1) {
                int z = __shfl_up(y, d, 64);
                if (lane >= d) y += z;
            }
            s_wave[lane] = y;
        }
        __syncthreads();
        int waveoff = (wv > 0) ? s_wave[wv - 1] : 0;
        int total = s_wave[3];
        if (i < nblk) blk_base[i] = x + waveoff + offset - v;   // exclusive
        offset += total;
        __syncthreads();
    }
}

__global__ void scan3_kernel(const int* __restrict__ cnt, const int* __restrict__ blk_base,
                             int* __restrict__ row_ptr, float* __restrict__ inv, int n) {
    __shared__ int s_wave[4];
    int t = threadIdx.x;
    int lane = t & 63, wv = t >> 6;
    int i = blockIdx.x * 256 + t;
    int v = (i < n) ? cnt[i] : 0;
    int x = v;
#pragma unroll
    for (int d = 1; d < 64; d <<= 1) {
        int y = __shfl_up(x, d, 64);
        if (lane >= d) x += y;
    }
    if (lane == 63) s_wave[wv] = x;
    __syncthreads();
    if (wv == 0 && lane < 4) {
        int y = s_wave[lane];
#pragma unroll
        for (int d = 1; d < 4; d <<= 1) {
            int z = __shfl_up(y, d, 64);
            if (lane >= d) y += z;
        }
        s_wave[lane] = y;
    }
    __syncthreads();
    int waveoff = (wv > 0) ? s_wave[wv - 1] : 0;
    if (i < n) {
        row_ptr[i + 1] = blk_base[blockIdx.x] + waveoff + x;
        inv[i] = 1.0f / (float)(v > 1 ? v : 1);
    }
    if (i == 0) row_ptr[0] = 0;
}

// Atomic-free placement: rec[row_ptr[dst]+rank[e]] = {src, ea}. One random
// 16B write per edge (single dirty line), sequential reads.
__global__ void place_kernel(const int* __restrict__ eidx, const float* __restrict__ ea,
                             const int* __restrict__ row_ptr, const int* __restrict__ rank,
                             fvec4* __restrict__ rec, int e_cnt) {
    int e = blockIdx.x * blockDim.x + threadIdx.x;
    if (e >= e_cnt) return;
    int src = eidx[e];
    int dst = eidx[e_cnt + e];
    int pos = row_ptr[dst] + rank[e];
    fvec4 r;
    r.x = __int_as_float(src);
    r.y = ea[3 * e];
    r.z = ea[3 * e + 1];
    r.w = ea[3 * e + 2];
    rec[pos] = r;
}

__global__ void h0_kernel(const float* __restrict__ x, const float* __restrict__ fc1_w,
                          const float* __restrict__ fc1_b, float* __restrict__ h, int n) {
    __shared__ float s_w[WN * 3];
    __shared__ float s_b[WN];
    int t = threadIdx.x;
    if (t < WN * 3) s_w[t] = fc1_w[t];
    if (t < WN) s_b[t] = fc1_b[t];
    __syncthreads();
    int i = blockIdx.x * blockDim.x + t;
    if (i >= n) return;
    float x0 = x[3 * i], x1 = x[3 * i + 1], x2 = x[3 * i + 2];
#pragma unroll
    for (int j = 0; j < WN; j++) {
        h[(size_t)i * WN + j] = s_b[j] + s_w[j * 3] * x0 + s_w[j * 3 + 1] * x1 + s_w[j * 3 + 2] * x2;
    }
}

// R6-proven cooperative gather, 2-channel register blocking. 16 node-groups
// x 16 threads; thread owns channels (2tc, 2tc+1). Per 32-edge chunk: threads
// stage 2 recs each (coalesced 16B loads), recompute hid in-register
// (kw1/kb1 scalarize to SGPRs), write conflict-free split u/v LDS arrays.
// Inner loop: LDS broadcast src/hid + independent coalesced float2 h-gather.
// Fused epilogue: mean + h@root + bias + relu.
__global__ void gather2_kernel(const int* __restrict__ row_ptr, const fvec4* __restrict__ rec,
                               const float* __restrict__ h_in, float* __restrict__ h_out,
                               const float* __restrict__ inv,
                               const float* __restrict__ kw1, const float* __restrict__ kb1,
                               const float* __restrict__ kw2, const float* __restrict__ kb2,
                               const float* __restrict__ root, const float* __restrict__ cbias,
                               int n) {
    __shared__ float s_root[WN * 34];        // row stride 34: float2-aligned, conflict-free
    __shared__ float s_h[GPB * 34];          // group stride 34
    __shared__ int   s_src[GPB][33];         // group stride 33 -> distinct banks per group
    __shared__ fvec4 s_hid_u[GPB][33];       // 16B lane stride writes: conflict-free
    __shared__ fvec4 s_hid_v[GPB][33];
    __shared__ int   s_maxdeg;

    int t = threadIdx.x;
    if (t == 0) s_maxdeg = 0;
    for (int i = t; i < WN * WN; i += 256) s_root[(i >> 5) * 34 + (i & 31)] = root[i];

    int grp = t >> 4;          // 0..15
    int tc  = t & 15;          // 0..15, channels 2tc, 2tc+1
    int node = blockIdx.x * GPB + grp;
    bool valid = node < n;

    // per-thread weight columns for 2 output channels (16 floats, coalesced)
    const fvec4* kwp = (const fvec4*)(kw2 + tc * 16);
    fvec4 wa0 = kwp[0], wa1 = kwp[1];        // channel 2tc
    fvec4 wb0 = kwp[2], wb1 = kwp[3];        // channel 2tc+1
    float2 b2 = *(const float2*)(kb2 + 2 * tc);
    float2 cb = *(const float2*)(cbias + 2 * tc);

    int e0 = 0, e1 = 0;
    float2 hself = {0.0f, 0.0f};
    if (valid) {
        e0 = row_ptr[node];
        e1 = row_ptr[node + 1];
        hself = *(const float2*)(h_in + (size_t)node * WN + 2 * tc);
    }
    *(float2*)&s_h[grp * 34 + 2 * tc] = hself;
    int deg = e1 - e0;
    __syncthreads();                         // s_maxdeg init + s_root/s_h visible
    if (valid && tc == 0 && deg > 0) atomicMax(&s_maxdeg, deg);
    __syncthreads();
    int nchunk = (s_maxdeg + 31) >> 5;       // block-uniform

    float acc0 = 0.0f, acc1 = 0.0f;
    for (int cs = 0; cs < nchunk; cs++) {
        int ebase = e0 + (cs << 5);
        // stage 32 edges: 2 per thread, hid recomputed in-register
#pragma unroll
        for (int s = 0; s < 2; s++) {
            int li = tc + (s << 4);
            int e = ebase + li;
            if (e < e1) {
                fvec4 r = rec[e];
                s_src[grp][li] = __float_as_int(r.x);
                float hv[HID];
#pragma unroll
                for (int j = 0; j < HID; j++) {
                    float u = kb1[j] + kw1[3 * j] * r.y + kw1[3 * j + 1] * r.z + kw1[3 * j + 2] * r.w;
                    hv[j] = u > 0.0f ? u : 0.0f;
                }
                fvec4 lo, hi;
                lo.x = hv[0]; lo.y = hv[1]; lo.z = hv[2]; lo.w = hv[3];
                hi.x = hv[4]; hi.y = hv[5]; hi.z = hv[6]; hi.w = hv[7];
                s_hid_u[grp][li] = lo;
                s_hid_v[grp][li] = hi;
            }
        }
        __syncthreads();
        int rem = e1 - ebase;
        int cnt = rem < 32 ? rem : 32;       // <=0 for finished/invalid groups
#pragma unroll 4
        for (int i = 0; i < cnt; i++) {
            int src = s_src[grp][i];
            fvec4 u = s_hid_u[grp][i];
            fvec4 v = s_hid_v[grp][i];
            float w0 = b2.x + wa0.x * u.x + wa0.y * u.y + wa0.z * u.z + wa0.w * u.w
                            + wa1.x * v.x + wa1.y * v.y + wa1.z * v.z + wa1.w * v.w;
            float w1 = b2.y + wb0.x * u.x + wb0.y * u.y + wb0.z * u.z + wb0.w * u.w
                            + wb1.x * v.x + wb1.y * v.y + wb1.z * v.z + wb1.w * v.w;
            float2 hh = *(const float2*)(h_in + (size_t)src * WN + 2 * tc);
            acc0 += hh.x * w0;
            acc1 += hh.y * w1;
        }
        __syncthreads();
    }
    if (!valid) return;

    float invn = inv[node];
    float r0 = acc0 * invn + cb.x;
    float r1 = acc1 * invn + cb.y;
#pragma unroll
    for (int k = 0; k < WN; k++) {
        float hk = s_h[grp * 34 + k];
        float2 rt = *(const float2*)&s_root[k * 34 + 2 * tc];
        r0 += hk * rt.x;
        r1 += hk * rt.y;
    }
    float2 o;
    o.x = r0 > 0.0f ? r0 : 0.0f;
    o.y = r1 > 0.0f ? r1 : 0.0f;
    *(float2*)(h_out + (size_t)node * WN + 2 * tc) = o;
}

__global__ void out_kernel(const float* __restrict__ h, const float* __restrict__ fc2_w,
                           const float* __restrict__ fc2_b, float* __restrict__ out, int n) {
    __shared__ float s_w[WN];
    __shared__ float s_b;
    int t = threadIdx.x;
    if (t < WN) s_w[t] = fc2_w[t];
    if (t == 0) s_b = fc2_b[0];
    __syncthreads();
    int i = blockIdx.x * blockDim.x + t;
    if (i >= n) return;
    float acc = s_b;
#pragma unroll
    for (int k = 0; k < WN; k++) acc += h[(size_t)i * WN + k] * s_w[k];
    out[i] = acc;
}

extern "C" void kernel_launch(void* const* d_in, const int* in_sizes, int n_in,
                              void* d_out, int out_size, void* d_ws, size_t ws_size,
                              hipStream_t stream) {
    const float* x      = (const float*)d_in[0];
    const int*   eidx   = (const int*)d_in[1];
    const float* ea     = (const float*)d_in[2];
    const float* fc1_w  = (const float*)d_in[3];
    const float* fc1_b  = (const float*)d_in[4];
    const float* fc2_w  = (const float*)d_in[5];
    const float* fc2_b  = (const float*)d_in[6];
    const float* kw1    = (const float*)d_in[7];
    const float* kb1    = (const float*)d_in[8];
    const float* kw2    = (const float*)d_in[9];
    const float* kb2    = (const float*)d_in[10];
    const float* root   = (const float*)d_in[11];
    const float* cbias  = (const float*)d_in[12];
    float* out = (float*)d_out;

    const int n = in_sizes[0] / 3;       // 50000
    const int e_cnt = in_sizes[2] / 3;   // 1600000

    // workspace layout (floats, 16B-aligned sections)
    auto pad4 = [](size_t v) { return (v + 3) & ~(size_t)3; };
    float* ws = (float*)d_ws;
    size_t off = 0;
    float* hA       = ws + off; off += pad4((size_t)n * WN);
    float* hB       = ws + off; off += pad4((size_t)n * WN);
    float* inv      = ws + off; off += pad4(n);
    int*   cnt      = (int*)(ws + off); off += pad4(n);
    int*   row_ptr  = (int*)(ws + off); off += pad4(n + 1);
    int*   blk_sum  = (int*)(ws + off); off += pad4((n + 255) / 256);
    int*   blk_base = (int*)(ws + off); off += pad4((n + 255) / 256);
    int*   rank     = (int*)(ws + off); off += pad4(e_cnt);
    fvec4* rec      = (fvec4*)(ws + off); off += (size_t)4 * e_cnt;

    const int B = 256;
    int grid_n  = (n + B - 1) / B;
    int grid_e  = (e_cnt + B - 1) / B;
    int nblk    = (n + 255) / 256;
    int grid_g  = (n + GPB - 1) / GPB;

    zero_kernel<<<grid_n, B, 0, stream>>>(cnt, n);
    rank_kernel<<<grid_e, B, 0, stream>>>(eidx, cnt, rank, e_cnt);
    scan1_kernel<<<nblk, B, 0, stream>>>(cnt, blk_sum, n);
    scan2_kernel<<<1, B, 0, stream>>>(blk_sum, blk_base, nblk);
    scan3_kernel<<<nblk, B, 0, stream>>>(cnt, blk_base, row_ptr, inv, n);
    place_kernel<<<grid_e, B, 0, stream>>>(eidx, ea, row_ptr, rank, rec, e_cnt);
    h0_kernel<<<grid_n, B, 0, stream>>>(x, fc1_w, fc1_b, hA, n);

    float* hin = hA;
    float* hout = hB;
    for (int d = 0; d < DEPTH; d++) {
        for (int c = 0; c < 3; c++) {
            gather2_kernel<<<grid_g, B, 0, stream>>>(
                row_ptr, rec, hin, hout, inv,
                kw1 + (size_t)c * HID * 3, kb1 + (size_t)c * HID,
                kw2 + (size_t)c * WN * HID, kb2 + (size_t)c * WN,
                root + (size_t)c * WN * WN, cbias + (size_t)c * WN, n);
            float* tmp = hin; hin = hout; hout = tmp;
        }
    }
    // 12 swaps -> final h is in hin
    out_kernel<<<grid_n, B, 0, stream>>>(hin, fc2_w, fc2_b, out, n);
}